// Round 1
// baseline (165.516 us; speedup 1.0000x reference)
//
#include <hip/hip_runtime.h>
#include <hip/hip_bf16.h>
#include <cstdint>
#include <cstddef>

#define N_SONGS 100000
#define EMBED   64
#define BATCH   1024
#define SEQL    200

typedef __attribute__((ext_vector_type(8))) __bf16 bf16x8;
typedef __attribute__((ext_vector_type(4))) float  f32x4;

__device__ __forceinline__ unsigned short f2b_rne(float x) {
    union { float f; uint32_t u; } v; v.f = x;
    uint32_t u = v.u;
    return (unsigned short)((u + 0x7FFFu + ((u >> 16) & 1u)) >> 16);
}

// ---------------- Kernel 1: W fp32 -> bf16 ----------------
__global__ __launch_bounds__(256) void wconv_kernel(const float* __restrict__ W,
                                                    unsigned short* __restrict__ wbf) {
    const int n4 = (N_SONGS * EMBED) / 4;   // 1,600,000 float4s
    int i = blockIdx.x * blockDim.x + threadIdx.x;
    int stride = gridDim.x * blockDim.x;
    for (; i < n4; i += stride) {
        float4 v = ((const float4*)W)[i];
        ushort4 o;
        o.x = f2b_rne(v.x); o.y = f2b_rne(v.y);
        o.z = f2b_rne(v.z); o.w = f2b_rne(v.w);
        ((ushort4*)wbf)[i] = o;
    }
}

// ---------------- Kernel 2: masked-mean pooling -> bf16 ----------------
__global__ __launch_bounds__(256) void pool_kernel(const int* __restrict__ songs,
                                                   const float* __restrict__ emb,
                                                   unsigned short* __restrict__ pooled) {
    int b = blockIdx.x;
    int t = threadIdx.x;
    int d = t & 63;        // embed dim
    int c = t >> 6;        // wave / L-chunk 0..3

    __shared__ float part[4][EMBED];
    __shared__ int   cnts[4];

    const int* row = songs + (size_t)b * SEQL;
    float acc = 0.f;
    int cnt = 0;
    int l0 = c * (SEQL / 4);
    for (int l = l0; l < l0 + SEQL / 4; ++l) {
        int id = row[l];                    // wave-uniform
        if (id != N_SONGS) {
            acc += emb[(size_t)id * EMBED + d];
            ++cnt;
        }
    }
    part[c][d] = acc;
    if (d == 0) cnts[c] = cnt;
    __syncthreads();
    if (t < EMBED) {
        float s = part[0][t] + part[1][t] + part[2][t] + part[3][t];
        float n = (float)(cnts[0] + cnts[1] + cnts[2] + cnts[3]);  // >= 1 always
        pooled[(size_t)b * EMBED + t] = f2b_rne(s / n);
    }
}

// ---------------- Kernel 3: [1024 x 100000] = sigmoid(pooled @ W^T + b) ----------------
// Block: 256 thr = 4 waves in 2x2, tile 128(M) x 128(N). K=64 in 2 mfma k-steps.
// Fragment layout (16x16x32 bf16): lane l holds row (l&15), k = (l>>4)*8 + e  -> 16B
// contiguous loads straight from row-major [.,64] bf16 operands (no LDS needed;
// pooled 128KB + W 12.8MB are cache-resident).
__global__ __launch_bounds__(256) void gemm_kernel(const unsigned short* __restrict__ pooled,
                                                   const unsigned short* __restrict__ wbf,
                                                   const float* __restrict__ bias,
                                                   float* __restrict__ out) {
    int nt = blockIdx.x, mt = blockIdx.y;
    int t = threadIdx.x;
    int w = t >> 6, lane = t & 63;
    int wm = w >> 1, wn = w & 1;
    int lr = lane & 15, lg = lane >> 4;

    int m0 = mt * 128 + wm * 64;
    int n0 = nt * 128 + wn * 64;

    // A fragments: pooled[m][k]
    bf16x8 afrag[2][4];
#pragma unroll
    for (int ks = 0; ks < 2; ++ks)
#pragma unroll
        for (int mi = 0; mi < 4; ++mi) {
            const unsigned short* p =
                pooled + (size_t)(m0 + mi * 16 + lr) * EMBED + ks * 32 + lg * 8;
            afrag[ks][mi] = *(const bf16x8*)p;
        }

    // B fragments: B[k][n] = W[n][k]; lane's 8 elems are contiguous k of W row (n0+nj*16+lr)
    bf16x8 bfrag[2][4];
#pragma unroll
    for (int ks = 0; ks < 2; ++ks)
#pragma unroll
        for (int nj = 0; nj < 4; ++nj) {
            int n = n0 + nj * 16 + lr;
            n = n < N_SONGS ? n : N_SONGS - 1;   // clamp; store is guarded
            const unsigned short* p = wbf + (size_t)n * EMBED + ks * 32 + lg * 8;
            bfrag[ks][nj] = *(const bf16x8*)p;
        }

    f32x4 acc[4][4];
#pragma unroll
    for (int mi = 0; mi < 4; ++mi)
#pragma unroll
        for (int nj = 0; nj < 4; ++nj)
            acc[mi][nj] = (f32x4){0.f, 0.f, 0.f, 0.f};

#pragma unroll
    for (int ks = 0; ks < 2; ++ks)
#pragma unroll
        for (int mi = 0; mi < 4; ++mi)
#pragma unroll
            for (int nj = 0; nj < 4; ++nj)
                acc[mi][nj] = __builtin_amdgcn_mfma_f32_16x16x32_bf16(
                    afrag[ks][mi], bfrag[ks][nj], acc[mi][nj], 0, 0, 0);

    // Epilogue: +bias, sigmoid, store. D layout: lane holds rows (lg*4 + r), col lr.
#pragma unroll
    for (int nj = 0; nj < 4; ++nj) {
        int n = n0 + nj * 16 + lr;
        if (n >= N_SONGS) continue;
        float bv = bias[n];
#pragma unroll
        for (int mi = 0; mi < 4; ++mi) {
            int m = m0 + mi * 16 + lg * 4;
#pragma unroll
            for (int r = 0; r < 4; ++r) {
                float x = acc[mi][nj][r] + bv;
                float e = __expf(-x);
                float s = __builtin_amdgcn_rcpf(1.0f + e);
                out[(size_t)(m + r) * N_SONGS + n] = s;
            }
        }
    }
}

extern "C" void kernel_launch(void* const* d_in, const int* in_sizes, int n_in,
                              void* d_out, int out_size, void* d_ws, size_t ws_size,
                              hipStream_t stream) {
    const int*   songs = (const int*)d_in[0];
    const float* emb   = (const float*)d_in[1];
    const float* W     = (const float*)d_in[2];
    const float* bias  = (const float*)d_in[3];
    float* out = (float*)d_out;

    unsigned short* wbf    = (unsigned short*)d_ws;                       // 12.8 MB
    unsigned short* pooled = wbf + (size_t)N_SONGS * EMBED;               // +128 KB

    hipLaunchKernelGGL(wconv_kernel, dim3(2048), dim3(256), 0, stream, W, wbf);
    hipLaunchKernelGGL(pool_kernel, dim3(BATCH), dim3(256), 0, stream, songs, emb, pooled);
    hipLaunchKernelGGL(gemm_kernel,
                       dim3((N_SONGS + 127) / 128, BATCH / 128), dim3(256), 0, stream,
                       pooled, wbf, bias, out);
}

// Round 2
// 133.708 us; speedup vs baseline: 1.2379x; 1.2379x over previous
//
#include <hip/hip_runtime.h>
#include <hip/hip_bf16.h>
#include <cstdint>
#include <cstddef>

#define N_SONGS 100000
#define EMBED   64
#define BATCH   1024
#define SEQL    200

typedef __attribute__((ext_vector_type(8)))  __bf16 bf16x8;
typedef __attribute__((ext_vector_type(16))) float  f32x16;

__device__ __forceinline__ unsigned short f2b_rne(float x) {
    union { float f; uint32_t u; } v; v.f = x;
    uint32_t u = v.u;
    return (unsigned short)((u + 0x7FFFu + ((u >> 16) & 1u)) >> 16);
}

// ---- Kernel 1: fused  [blocks 0..2047]: W fp32->bf16   [blocks 2048..3071]: masked-mean pool ----
__global__ __launch_bounds__(256) void prep_kernel(const float* __restrict__ W,
                                                   unsigned short* __restrict__ wbf,
                                                   const int* __restrict__ songs,
                                                   const float* __restrict__ emb,
                                                   unsigned short* __restrict__ pooled) {
    __shared__ float part[4][EMBED];
    __shared__ int   cnts[4];

    if (blockIdx.x < 2048) {
        // ---- W conversion, grid-stride over float4s ----
        const int n4 = (N_SONGS * EMBED) / 4;   // 1,600,000
        int i = blockIdx.x * 256 + threadIdx.x;
        for (; i < n4; i += 2048 * 256) {
            float4 v = ((const float4*)W)[i];
            ushort4 o;
            o.x = f2b_rne(v.x); o.y = f2b_rne(v.y);
            o.z = f2b_rne(v.z); o.w = f2b_rne(v.w);
            ((ushort4*)wbf)[i] = o;
        }
    } else {
        // ---- pooling: one block per sample ----
        int b = blockIdx.x - 2048;
        int t = threadIdx.x;
        int d = t & 63;        // embed dim
        int c = t >> 6;        // L-chunk 0..3

        const int* row = songs + (size_t)b * SEQL;
        float acc = 0.f;
        int cnt = 0;
        int l0 = c * (SEQL / 4);
        for (int l = l0; l < l0 + SEQL / 4; ++l) {
            int id = row[l];                    // wave-uniform
            if (id != N_SONGS) {
                acc += emb[(size_t)id * EMBED + d];
                ++cnt;
            }
        }
        part[c][d] = acc;
        if (d == 0) cnts[c] = cnt;
        __syncthreads();
        if (t < EMBED) {
            float s = part[0][t] + part[1][t] + part[2][t] + part[3][t];
            float n = (float)(cnts[0] + cnts[1] + cnts[2] + cnts[3]);  // >= 1 always
            pooled[(size_t)b * EMBED + t] = f2b_rne(s / n);
        }
    }
}

// ---- Kernel 2: out[1024 x 100000] = sigmoid(pooled @ W^T + b), 32x32x16 MFMA ----
// Block 256 thr = 4 waves (2x2), tile 128x128; wave tile 64x64 via 2x2 frags of 32x32.
// A/B operand layout: lane holds row/col = lane&31, k = ks*16 + (lane>>5)*8 + e  -> 16B
// contiguous from row-major [.,64] bf16 (cache-resident; no LDS).
// D layout: col = lane&31, row = (r&3) + 8*(r>>2) + 4*(lane>>5)  -> each store instr
// covers 2 rows x 32 cols x 4B = two 128B-aligned FULL cache lines (row stride
// 400000 B = 3125*128; col offsets multiples of 32 floats).
__global__ __launch_bounds__(256) void gemm_kernel(const unsigned short* __restrict__ pooled,
                                                   const unsigned short* __restrict__ wbf,
                                                   const float* __restrict__ bias,
                                                   float* __restrict__ out) {
    int nt = blockIdx.x, mt = blockIdx.y;
    int t = threadIdx.x;
    int w = t >> 6, lane = t & 63;
    int wm = w >> 1, wn = w & 1;
    int lc = lane & 31;      // row (A) / col (B,D) within 32
    int hi = lane >> 5;      // k-half selector

    int m0 = mt * 128 + wm * 64;
    int n0 = nt * 128 + wn * 64;

    // A fragments: pooled[m][k]
    bf16x8 afrag[4][2];
#pragma unroll
    for (int ks = 0; ks < 4; ++ks)
#pragma unroll
        for (int mi = 0; mi < 2; ++mi) {
            const unsigned short* p =
                pooled + (size_t)(m0 + mi * 32 + lc) * EMBED + ks * 16 + hi * 8;
            afrag[ks][mi] = *(const bf16x8*)p;
        }

    // B fragments: B[k][n] = W[n][k]
    bf16x8 bfrag[4][2];
#pragma unroll
    for (int ks = 0; ks < 4; ++ks)
#pragma unroll
        for (int nj = 0; nj < 2; ++nj) {
            int n = n0 + nj * 32 + lc;
            n = n < N_SONGS ? n : N_SONGS - 1;   // clamp; store is guarded
            const unsigned short* p = wbf + (size_t)n * EMBED + ks * 16 + hi * 8;
            bfrag[ks][nj] = *(const bf16x8*)p;
        }

    f32x16 acc[2][2];
#pragma unroll
    for (int mi = 0; mi < 2; ++mi)
#pragma unroll
        for (int nj = 0; nj < 2; ++nj)
#pragma unroll
            for (int r = 0; r < 16; ++r)
                acc[mi][nj][r] = 0.f;

#pragma unroll
    for (int ks = 0; ks < 4; ++ks)
#pragma unroll
        for (int mi = 0; mi < 2; ++mi)
#pragma unroll
            for (int nj = 0; nj < 2; ++nj)
                acc[mi][nj] = __builtin_amdgcn_mfma_f32_32x32x16_bf16(
                    afrag[ks][mi], bfrag[ks][nj], acc[mi][nj], 0, 0, 0);

    // Epilogue: +bias, sigmoid, store (full-line 128B segments)
#pragma unroll
    for (int nj = 0; nj < 2; ++nj) {
        int n = n0 + nj * 32 + lc;
        if (n >= N_SONGS) continue;
        float bv = bias[n];
#pragma unroll
        for (int mi = 0; mi < 2; ++mi) {
#pragma unroll
            for (int r = 0; r < 16; ++r) {
                int row = m0 + mi * 32 + (r & 3) + 8 * (r >> 2) + 4 * hi;
                float x = acc[mi][nj][r] + bv;
                float e = __expf(-x);
                float s = __builtin_amdgcn_rcpf(1.0f + e);
                out[(size_t)row * N_SONGS + n] = s;
            }
        }
    }
}

extern "C" void kernel_launch(void* const* d_in, const int* in_sizes, int n_in,
                              void* d_out, int out_size, void* d_ws, size_t ws_size,
                              hipStream_t stream) {
    const int*   songs = (const int*)d_in[0];
    const float* emb   = (const float*)d_in[1];
    const float* W     = (const float*)d_in[2];
    const float* bias  = (const float*)d_in[3];
    float* out = (float*)d_out;

    unsigned short* wbf    = (unsigned short*)d_ws;                       // 12.8 MB
    unsigned short* pooled = wbf + (size_t)N_SONGS * EMBED;               // +128 KB

    hipLaunchKernelGGL(prep_kernel, dim3(2048 + BATCH), dim3(256), 0, stream,
                       W, wbf, songs, emb, pooled);
    hipLaunchKernelGGL(gemm_kernel,
                       dim3((N_SONGS + 127) / 128, BATCH / 128), dim3(256), 0, stream,
                       pooled, wbf, bias, out);
}

// Round 4
// 112.527 us; speedup vs baseline: 1.4709x; 1.1882x over previous
//
#include <hip/hip_runtime.h>
#include <hip/hip_bf16.h>
#include <cstdint>
#include <cstddef>

#define N_SONGS 100000
#define EMBED   64
#define BATCH   1024
#define SEQL    200

typedef __attribute__((ext_vector_type(8)))  __bf16 bf16x8;
typedef __attribute__((ext_vector_type(16))) float  f32x16;
typedef __attribute__((ext_vector_type(4)))  float  f32x4;

__device__ __forceinline__ unsigned short f2b_rne(float x) {
    union { float f; uint32_t u; } v; v.f = x;
    uint32_t u = v.u;
    return (unsigned short)((u + 0x7FFFu + ((u >> 16) & 1u)) >> 16);
}

// ---- Kernel 1: fused  [blocks 0..2047]: W fp32->bf16   [blocks 2048..3071]: masked-mean pool ----
__global__ __launch_bounds__(256) void prep_kernel(const float* __restrict__ W,
                                                   unsigned short* __restrict__ wbf,
                                                   const int* __restrict__ songs,
                                                   const float* __restrict__ emb,
                                                   unsigned short* __restrict__ pooled) {
    __shared__ float part[4][EMBED];
    __shared__ int   cnts[4];

    if (blockIdx.x < 2048) {
        // ---- W conversion, grid-stride over float4s; NT loads (read-once) ----
        const int n4 = (N_SONGS * EMBED) / 4;   // 1,600,000
        int i = blockIdx.x * 256 + threadIdx.x;
        for (; i < n4; i += 2048 * 256) {
            f32x4 v = __builtin_nontemporal_load(&((const f32x4*)W)[i]);
            ushort4 o;
            o.x = f2b_rne(v.x); o.y = f2b_rne(v.y);
            o.z = f2b_rne(v.z); o.w = f2b_rne(v.w);
            ((ushort4*)wbf)[i] = o;   // keep cached: consumed by gemm
        }
    } else {
        // ---- pooling: one block per sample ----
        int b = blockIdx.x - 2048;
        int t = threadIdx.x;
        int d = t & 63;        // embed dim
        int c = t >> 6;        // L-chunk 0..3

        const int* row = songs + (size_t)b * SEQL;
        float acc = 0.f;
        int cnt = 0;
        int l0 = c * (SEQL / 4);
        for (int l = l0; l < l0 + SEQL / 4; ++l) {
            int id = row[l];                    // wave-uniform
            if (id != N_SONGS) {
                acc += emb[(size_t)id * EMBED + d];
                ++cnt;
            }
        }
        part[c][d] = acc;
        if (d == 0) cnts[c] = cnt;
        __syncthreads();
        if (t < EMBED) {
            float s = part[0][t] + part[1][t] + part[2][t] + part[3][t];
            float n = (float)(cnts[0] + cnts[1] + cnts[2] + cnts[3]);  // >= 1 always
            pooled[(size_t)b * EMBED + t] = f2b_rne(s / n);
        }
    }
}

// ---- Kernel 2: out[1024 x 100000] = sigmoid(pooled @ W^T + b), 32x32x16 MFMA ----
// Block 256 thr = 4 waves (2x2), tile 128x128; wave tile 64x64 via 2x2 frags of 32x32.
// D layout: col = lane&31, row = (r&3) + 8*(r>>2) + 4*(lane>>5) -> each store instr
// covers two 128B-aligned full cache lines. Output is write-once -> non-temporal
// stores keep the 400MB stream from evicting W-bf16/pooled out of L2.
__global__ __launch_bounds__(256, 2) void gemm_kernel(const unsigned short* __restrict__ pooled,
                                                      const unsigned short* __restrict__ wbf,
                                                      const float* __restrict__ bias,
                                                      float* __restrict__ out) {
    int nt = blockIdx.x, mt = blockIdx.y;
    int t = threadIdx.x;
    int w = t >> 6, lane = t & 63;
    int wm = w >> 1, wn = w & 1;
    int lc = lane & 31;      // row (A) / col (B,D) within 32
    int hi = lane >> 5;      // k-half selector

    int m0 = mt * 128 + wm * 64;
    int n0 = nt * 128 + wn * 64;

    // A fragments: pooled[m][k]
    bf16x8 afrag[4][2];
#pragma unroll
    for (int ks = 0; ks < 4; ++ks)
#pragma unroll
        for (int mi = 0; mi < 2; ++mi) {
            const unsigned short* p =
                pooled + (size_t)(m0 + mi * 32 + lc) * EMBED + ks * 16 + hi * 8;
            afrag[ks][mi] = *(const bf16x8*)p;
        }

    // B fragments: B[k][n] = W[n][k]
    bf16x8 bfrag[4][2];
#pragma unroll
    for (int ks = 0; ks < 4; ++ks)
#pragma unroll
        for (int nj = 0; nj < 2; ++nj) {
            int n = n0 + nj * 32 + lc;
            n = n < N_SONGS ? n : N_SONGS - 1;   // clamp; store is guarded
            const unsigned short* p = wbf + (size_t)n * EMBED + ks * 16 + hi * 8;
            bfrag[ks][nj] = *(const bf16x8*)p;
        }

    f32x16 acc[2][2];
#pragma unroll
    for (int mi = 0; mi < 2; ++mi)
#pragma unroll
        for (int nj = 0; nj < 2; ++nj)
#pragma unroll
            for (int r = 0; r < 16; ++r)
                acc[mi][nj][r] = 0.f;

#pragma unroll
    for (int ks = 0; ks < 4; ++ks)
#pragma unroll
        for (int mi = 0; mi < 2; ++mi)
#pragma unroll
            for (int nj = 0; nj < 2; ++nj)
                acc[mi][nj] = __builtin_amdgcn_mfma_f32_32x32x16_bf16(
                    afrag[ks][mi], bfrag[ks][nj], acc[mi][nj], 0, 0, 0);

    // Epilogue: +bias, sigmoid, non-temporal store
#pragma unroll
    for (int nj = 0; nj < 2; ++nj) {
        int n = n0 + nj * 32 + lc;
        if (n >= N_SONGS) continue;
        float bv = bias[n];
#pragma unroll
        for (int mi = 0; mi < 2; ++mi) {
#pragma unroll
            for (int r = 0; r < 16; ++r) {
                int row = m0 + mi * 32 + (r & 3) + 8 * (r >> 2) + 4 * hi;
                float x = acc[mi][nj][r] + bv;
                float e = __expf(-x);
                float s = __builtin_amdgcn_rcpf(1.0f + e);
                __builtin_nontemporal_store(s, &out[(size_t)row * N_SONGS + n]);
            }
        }
    }
}

extern "C" void kernel_launch(void* const* d_in, const int* in_sizes, int n_in,
                              void* d_out, int out_size, void* d_ws, size_t ws_size,
                              hipStream_t stream) {
    const int*   songs = (const int*)d_in[0];
    const float* emb   = (const float*)d_in[1];
    const float* W     = (const float*)d_in[2];
    const float* bias  = (const float*)d_in[3];
    float* out = (float*)d_out;

    unsigned short* wbf    = (unsigned short*)d_ws;                       // 12.8 MB
    unsigned short* pooled = wbf + (size_t)N_SONGS * EMBED;               // +128 KB

    hipLaunchKernelGGL(prep_kernel, dim3(2048 + BATCH), dim3(256), 0, stream,
                       W, wbf, songs, emb, pooled);
    hipLaunchKernelGGL(gemm_kernel,
                       dim3((N_SONGS + 127) / 128, BATCH / 128), dim3(256), 0, stream,
                       pooled, wbf, bias, out);
}